// Round 1
// baseline (225.161 us; speedup 1.0000x reference)
//
#include <hip/hip_runtime.h>

#define NB 32            // batch
#define NT 1024          // input time steps
#define ND 384           // feature dim
#define ND4 (ND / 4)     // 96 float4 per frame
#define FPW 4            // frames per wave
#define WPB 4            // waves per block (256 threads)
#define FPB (FPW * WPB)  // 16 frames per block

typedef float vfloat4 __attribute__((ext_vector_type(4)));

// Kernel 1: one block per batch. Wave-shuffle inclusive scan of durations ->
// csum (coalesced 128 KB instead of the old 474 KB scattered idx), plus
// zero-fill of the pad region [total, max_len) of out.
__global__ void __launch_bounds__(NT)
scan_pad_kernel(const int* __restrict__ dur,
                int* __restrict__ csum,
                vfloat4* __restrict__ out,
                int max_len) {
    __shared__ int wsum[16];
    const int b = blockIdx.x;
    const int t = threadIdx.x;
    const int lane = t & 63;
    const int w = t >> 6;                 // wave id, 16 waves
    const int d = dur[b * NT + t];

    // intra-wave inclusive scan (64 lanes, 6 shuffle steps)
    int x = d;
    #pragma unroll
    for (int off = 1; off < 64; off <<= 1) {
        int y = __shfl_up(x, off, 64);
        if (lane >= off) x += y;
    }
    if (lane == 63) wsum[w] = x;
    __syncthreads();
    if (w == 0) {
        int v = (lane < 16) ? wsum[lane] : 0;
        #pragma unroll
        for (int off = 1; off < 16; off <<= 1) {
            int y = __shfl_up(v, off, 64);
            if (lane >= off) v += y;
        }
        if (lane < 16) wsum[lane] = v;    // inclusive per-wave totals
    }
    __syncthreads();
    const int c = x + (w ? wsum[w - 1] : 0);
    const int total = wsum[15];
    csum[b * NT + t] = c;                 // coalesced dword write

    // zero-fill pad frames [total, max_len)
    vfloat4* out_b = out + (size_t)b * max_len * ND4;
    const vfloat4 z = {0.f, 0.f, 0.f, 0.f};
    const int end = max_len * ND4;
    for (int i = total * ND4 + t; i < end; i += NT)
        __builtin_nontemporal_store(z, &out_b[i]);
}

// Kernel 2: write-centric expansion. grid = (NT/FPB, NB), 256 threads.
// Each wave owns FPW consecutive input frames: loads each frame ONCE
// (96 float4 = 64 lanes + 32 masked), then stores it d times to the
// consecutive output slots [csum[f-1], csum[f]). Trip counts are
// wave-uniform (no divergence); all loads are independent and issued
// up-front (8 outstanding 1.5 KB loads per wave).
__global__ void __launch_bounds__(256)
expand_kernel(const vfloat4* __restrict__ enc,
              const int* __restrict__ csum,
              vfloat4* __restrict__ out,
              int max_len) {
    const int b = blockIdx.y;
    const int lane = threadIdx.x & 63;
    const int wv = threadIdx.x >> 6;
    const int f0 = blockIdx.x * FPB + wv * FPW;

    const int* csum_b = csum + b * NT;
    const vfloat4* enc_b = enc + (size_t)b * NT * ND4;
    vfloat4* out_b = out + (size_t)b * (size_t)max_len * ND4;

    // segment bounds (wave-uniform; broadcast loads from L1/L2)
    int e[FPW], s[FPW];
    #pragma unroll
    for (int k = 0; k < FPW; ++k)
        e[k] = csum_b[f0 + k];
    s[0] = f0 ? csum_b[f0 - 1] : 0;
    #pragma unroll
    for (int k = 1; k < FPW; ++k)
        s[k] = e[k - 1];

    // load all FPW frames up-front: 96 f4 = lanes 0-63 + lanes 0-31
    vfloat4 v0[FPW], v1[FPW];
    #pragma unroll
    for (int k = 0; k < FPW; ++k) {
        const vfloat4* src = enc_b + (size_t)(f0 + k) * ND4;
        v0[k] = src[lane];
        if (lane < 32) v1[k] = src[64 + lane];
    }

    // replicate: each rep is a coalesced 1 KB + 512 B store
    #pragma unroll
    for (int k = 0; k < FPW; ++k) {
        for (int p = s[k]; p < e[k]; ++p) {
            vfloat4* dst = out_b + (size_t)p * ND4;
            __builtin_nontemporal_store(v0[k], dst + lane);
            if (lane < 32)
                __builtin_nontemporal_store(v1[k], dst + 64 + lane);
        }
    }
}

extern "C" void kernel_launch(void* const* d_in, const int* in_sizes, int n_in,
                              void* d_out, int out_size, void* d_ws, size_t ws_size,
                              hipStream_t stream) {
    const float* enc = (const float*)d_in[0];
    const int*   dur = (const int*)d_in[1];
    float* out = (float*)d_out;

    const int max_len = out_size / (NB * ND);   // out_size = NB*max_len*ND

    // ws layout: [csum: NB*NT ints] (128 KB)
    int* csum = (int*)d_ws;

    scan_pad_kernel<<<NB, NT, 0, stream>>>(dur, csum, (vfloat4*)out, max_len);

    dim3 grid(NT / FPB, NB);   // (64, 32)
    expand_kernel<<<grid, 256, 0, stream>>>(
        (const vfloat4*)enc, csum, (vfloat4*)out, max_len);
}

// Round 2
// 219.554 us; speedup vs baseline: 1.0255x; 1.0255x over previous
//
#include <hip/hip_runtime.h>

#define NB 32            // batch
#define NT 1024          // input time steps
#define ND 384           // feature dim
#define ND4 (ND / 4)     // 96 float4 per frame
#define FPW 4            // frames per wave
#define WPB 4            // waves per block (256 threads)
#define FPB (FPW * WPB)  // 16 frames per block
#define NBX (NT / FPB)   // 64 blocks per batch
#define THREADS 256

typedef float vfloat4 __attribute__((ext_vector_type(4)));
typedef int   vint4   __attribute__((ext_vector_type(4)));

// Single fused kernel. grid = (NBX, NB), 256 threads.
//
// Phase 1 (block-redundant scan): every block loads all 1024 durations of
// its batch (4 KB, L2-resident) and computes the inclusive csum into LDS.
// ~2 us of shuffle work; removes the separate scan kernel, its launch gap,
// and the csum global-memory round-trip.
//
// Phase 2 (write-centric expand): each wave owns FPW consecutive frames,
// loads each frame once into THREE register images:
//   v0[l] = elem l, v1[l] = elem (64+l)%96, v2[l] = elem 32+l
// so a PAIR of reps (192 f4, contiguous) is exactly 3 full-wave 1 KB
// b128 stores -- no masked half-width stores in the steady state.
// Plain stores (not nontemporal) this round: A/B vs the nt path that both
// previous ~110us variants shared.
__global__ void __launch_bounds__(THREADS)
fused_expand_kernel(const vfloat4* __restrict__ enc,
                    const int* __restrict__ dur,
                    vfloat4* __restrict__ out,
                    int max_len) {
    __shared__ int sm_csum[NT];
    __shared__ int wsum[WPB];

    const int b    = blockIdx.y;
    const int bx   = blockIdx.x;
    const int t    = threadIdx.x;
    const int lane = t & 63;
    const int wv   = t >> 6;

    // ---- phase 1: block scan of 1024 durations -> sm_csum, total
    vint4 d4 = *(const vint4*)(dur + b * NT + 4 * t);
    const int l0 = d4.x;
    const int l1 = l0 + d4.y;
    const int l2 = l1 + d4.z;
    const int l3 = l2 + d4.w;
    const int S  = l3;

    int x = S;                       // wave-inclusive scan of thread sums
    #pragma unroll
    for (int off = 1; off < 64; off <<= 1) {
        int y = __shfl_up(x, off, 64);
        if (lane >= off) x += y;
    }
    if (lane == 63) wsum[wv] = x;
    __syncthreads();
    if (t == 0) {                    // serial scan of 4 wave totals
        int a = 0;
        #pragma unroll
        for (int i = 0; i < WPB; ++i) { a += wsum[i]; wsum[i] = a; }
    }
    __syncthreads();
    const int P = (wv ? wsum[wv - 1] : 0) + (x - S);   // thread-exclusive prefix
    sm_csum[4 * t + 0] = P + l0;
    sm_csum[4 * t + 1] = P + l1;
    sm_csum[4 * t + 2] = P + l2;
    sm_csum[4 * t + 3] = P + l3;
    const int total = wsum[WPB - 1];
    __syncthreads();

    // ---- phase 2: expansion
    const int f0 = bx * FPB + wv * FPW;
    const vfloat4* enc_b = enc + (size_t)b * NT * ND4;
    vfloat4*       out_b = out + (size_t)b * (size_t)max_len * ND4;

    const int s0 = (f0 == 0) ? 0 : sm_csum[f0 - 1];
    int e[FPW];
    #pragma unroll
    for (int k = 0; k < FPW; ++k)
        e[k] = sm_csum[f0 + k];

    // three register images per frame (12 independent loads, L1-overlapping)
    const int i1 = (lane < 32) ? (64 + lane) : (lane - 32);
    vfloat4 v0[FPW], v1[FPW], v2[FPW];
    #pragma unroll
    for (int k = 0; k < FPW; ++k) {
        const vfloat4* src = enc_b + (size_t)(f0 + k) * ND4;
        v0[k] = src[lane];
        v1[k] = src[i1];
        v2[k] = src[32 + lane];
    }

    // replicate: pairs of reps = 3 full-wave 1 KB stores; odd tail = 1.5
    #pragma unroll
    for (int k = 0; k < FPW; ++k) {
        int p = (k == 0) ? s0 : e[k - 1];
        const int ee = e[k];
        for (; p + 2 <= ee; p += 2) {
            vfloat4* dst = out_b + (size_t)p * ND4;
            dst[lane]        = v0[k];
            dst[64 + lane]   = v1[k];
            dst[128 + lane]  = v2[k];
        }
        if (p < ee) {
            vfloat4* dst = out_b + (size_t)p * ND4;
            dst[lane] = v0[k];
            if (lane < 32) dst[64 + lane] = v1[k];   // v1[l<32] = elem 64+l
        }
    }

    // ---- pad fill [total, max_len), spread across all NBX blocks of batch b
    const int end4 = max_len * ND4;
    const vfloat4 z = {0.f, 0.f, 0.f, 0.f};
    for (int i = total * ND4 + bx * THREADS + t; i < end4; i += NBX * THREADS)
        out_b[i] = z;
}

extern "C" void kernel_launch(void* const* d_in, const int* in_sizes, int n_in,
                              void* d_out, int out_size, void* d_ws, size_t ws_size,
                              hipStream_t stream) {
    const float* enc = (const float*)d_in[0];
    const int*   dur = (const int*)d_in[1];
    float* out = (float*)d_out;

    const int max_len = out_size / (NB * ND);   // out_size = NB*max_len*ND

    dim3 grid(NBX, NB);   // (64, 32)
    fused_expand_kernel<<<grid, THREADS, 0, stream>>>(
        (const vfloat4*)enc, dur, (vfloat4*)out, max_len);
}